// Round 7
// baseline (609.169 us; speedup 1.0000x reference)
//
#include <hip/hip_runtime.h>
#include <hip/hip_fp16.h>
#include <math.h>

#define VOCAB 100000
#define HID 256
#define BATCH 4096
#define BN_EPS 1e-5f
#define TPB1 512      // tokens per range in k1
#define NSHARD 8      // column shards == XCD count

// ws layout (in floats)
#define WS_SEGSUM 0
#define WS_COUNTS (BATCH * HID)            // 1048576
#define WS_COLSUM (WS_COUNTS + BATCH)
#define WS_COLSQ  (WS_COLSUM + HID)
#define WS_ZERO_FLOATS (WS_COLSQ + HID)    // zero-filled by k0
#define WS_EMB16_OFF_BYTES ((size_t)WS_ZERO_FLOATS * 4)   // 16B-aligned
#define WS_FP16_BYTES_NEEDED (WS_EMB16_OFF_BYTES + (size_t)VOCAB * HID * 2)

// ---------------------------------------------------------------------------
// k0: emb fp32 -> fp16 table in ws; also zeroes the accumulator region.
// ---------------------------------------------------------------------------
__global__ __launch_bounds__(256) void k0_convert_zero(
    const float* __restrict__ emb, __half* __restrict__ emb16,
    float4* __restrict__ zws, int n4, int nz4)
{
    int i = blockIdx.x * 256 + threadIdx.x;
    if (i < nz4) zws[i] = make_float4(0.f, 0.f, 0.f, 0.f);
    if (i >= n4) return;
    float4 v = reinterpret_cast<const float4*>(emb)[i];
    __half2 a = __halves2half2(__float2half_rn(v.x), __float2half_rn(v.y));
    __half2 b = __halves2half2(__float2half_rn(v.z), __float2half_rn(v.w));
    uint2 o;
    o.x = __builtin_bit_cast(unsigned int, a);
    o.y = __builtin_bit_cast(unsigned int, b);
    reinterpret_cast<uint2*>(emb16)[i] = o;
}

// ---------------------------------------------------------------------------
// k1 v5 (fp16, COLUMN-sharded for XCD/L2 locality): 8 blocks per 512-token
// range; block range*8+s processes ALL tokens of the range but only columns
// [32s, 32s+32) = one 64B cache line per vocab row -> per-shard working set
// 6.4 MB, L2-resident on its XCD if the CP round-robins blockIdx%8 over
// XCDs (r6 evidence: FETCH 192->123 MB). Unlike token-sharding (r6), flush
// bytes are INVARIANT: each (block,run) writes only its 128B slice, total
// atomic traffic == unsharded (~42 MB).
// Lane = group g (lane>>3) x chunk c (lane&7): group g walks tokens at
// stride 8; lane reads uint2 (4 halves) at row[s*32 + c*4]. Run tracking is
// per-group; boundary flushes diverge <=1 iteration between groups (rare,
// exec-masked). Counts: only shard 0, c==0 lanes add group runlens.
// ---------------------------------------------------------------------------
__global__ __launch_bounds__(256) void k1_gather_fp16_cs(
    const int* __restrict__ token_ids, const int* __restrict__ segment_ids,
    const __half* __restrict__ emb16, float* __restrict__ seg_sum,
    float* __restrict__ counts, int T)
{
    __shared__ int s_tok[TPB1];
    __shared__ int s_seg[TPB1];
    const int tid   = threadIdx.x;
    const int range = blockIdx.x >> 3;
    const int shard = blockIdx.x & 7;
    const int t0    = range * TPB1;
    const int n     = min(TPB1, T - t0);
    if (n <= 0) return;
    for (int i = tid; i < n; i += 256) {
        s_tok[i] = token_ids[t0 + i];
        s_seg[i] = segment_ids[t0 + i];
    }
    __syncthreads();

    const int wave = tid >> 6;
    const int lane = tid & 63;
    const int g    = lane >> 3;        // token group 0..7 (stride-8 walk)
    const int c    = lane & 7;         // column sub-chunk 0..7
    const int col  = shard * 8 + c;    // uint2 index within the 64-uint2 row
    const int per  = TPB1 / 4;         // 128 tokens per wave
    const int start = wave * per;
    const int end   = min(start + per, n);
    int i = start + g;
    if (i >= end) return;              // no __syncthreads after this point

    const uint2* __restrict__ embv = reinterpret_cast<const uint2*>(emb16);
    float4 acc = make_float4(0.f, 0.f, 0.f, 0.f);
    int cur    = s_seg[i];
    int runlen = 0;

#define K1_FLUSH() do {                                                        \
        float* p = &seg_sum[(size_t)cur * HID + col * 4];                      \
        atomicAdd(p + 0, acc.x); atomicAdd(p + 1, acc.y);                      \
        atomicAdd(p + 2, acc.z); atomicAdd(p + 3, acc.w);                      \
        if (shard == 0 && c == 0) atomicAdd(&counts[cur], (float)runlen);      \
        acc = make_float4(0.f, 0.f, 0.f, 0.f); runlen = 0;                     \
    } while (0)

#define K1_PROC(ii, u) do {                                                    \
        int seg = s_seg[ii];                                                   \
        if (seg != cur) { K1_FLUSH(); cur = seg; }                             \
        __half2 h01 = __builtin_bit_cast(__half2, (u).x);                      \
        __half2 h23 = __builtin_bit_cast(__half2, (u).y);                      \
        float2 f01 = __half22float2(h01);                                      \
        float2 f23 = __half22float2(h23);                                      \
        acc.x += f01.x; acc.y += f01.y; acc.z += f23.x; acc.w += f23.y;        \
        runlen++;                                                              \
    } while (0)

    // 4 stride-8 tokens in flight per lane (32 tokens/group-iteration)
    for (; i + 24 < end; i += 32) {
        uint2 u0 = embv[(size_t)s_tok[i +  0] * 64 + col];
        uint2 u1 = embv[(size_t)s_tok[i +  8] * 64 + col];
        uint2 u2 = embv[(size_t)s_tok[i + 16] * 64 + col];
        uint2 u3 = embv[(size_t)s_tok[i + 24] * 64 + col];
        K1_PROC(i +  0, u0);
        K1_PROC(i +  8, u1);
        K1_PROC(i + 16, u2);
        K1_PROC(i + 24, u3);
    }
    for (; i < end; i += 8) {
        uint2 u = embv[(size_t)s_tok[i] * 64 + col];
        K1_PROC(i, u);
    }
    K1_FLUSH();
#undef K1_PROC
#undef K1_FLUSH
}

// ---------------------------------------------------------------------------
// k1 (fp32 fallback, only if ws too small for the fp16 table).
// ---------------------------------------------------------------------------
__global__ __launch_bounds__(256) void k1_gather_fp32(
    const int* __restrict__ token_ids, const int* __restrict__ segment_ids,
    const float* __restrict__ emb, float* __restrict__ seg_sum,
    float* __restrict__ counts, int T)
{
    __shared__ int s_tok[TPB1];
    __shared__ int s_seg[TPB1];
    const int tid = threadIdx.x;
    const int t0  = blockIdx.x * TPB1;
    const int n   = min(TPB1, T - t0);
    if (n <= 0) return;
    for (int i = tid; i < n; i += 256) {
        s_tok[i] = token_ids[t0 + i];
        s_seg[i] = segment_ids[t0 + i];
    }
    __syncthreads();

    const int wave = tid >> 6;
    const int lane = tid & 63;
    const int per  = TPB1 / 4;
    const int start = wave * per;
    const int end   = min(start + per, n);
    if (start >= end) return;

    const float4* __restrict__ embv = reinterpret_cast<const float4*>(emb);
    float4 acc = make_float4(0.f, 0.f, 0.f, 0.f);
    int cur = s_seg[start];
    int runlen = 0;

#define K1_FLUSH() do {                                                        \
        float* p = &seg_sum[(size_t)cur * HID + lane * 4];                     \
        atomicAdd(p + 0, acc.x); atomicAdd(p + 1, acc.y);                      \
        atomicAdd(p + 2, acc.z); atomicAdd(p + 3, acc.w);                      \
        if (lane == 0) atomicAdd(&counts[cur], (float)runlen);                 \
        acc = make_float4(0.f, 0.f, 0.f, 0.f); runlen = 0;                     \
    } while (0)

#define K1_PROC(ii, v) do {                                                    \
        int seg = s_seg[ii];                                                   \
        if (seg != cur) { K1_FLUSH(); cur = seg; }                             \
        acc.x += (v).x; acc.y += (v).y; acc.z += (v).z; acc.w += (v).w;        \
        runlen++;                                                              \
    } while (0)

    const int m4 = start + ((end - start) & ~3);
    for (int i = start; i < m4; i += 4) {
        float4 a0 = embv[(size_t)s_tok[i + 0] * 64 + lane];
        float4 a1 = embv[(size_t)s_tok[i + 1] * 64 + lane];
        float4 a2 = embv[(size_t)s_tok[i + 2] * 64 + lane];
        float4 a3 = embv[(size_t)s_tok[i + 3] * 64 + lane];
        K1_PROC(i + 0, a0); K1_PROC(i + 1, a1);
        K1_PROC(i + 2, a2); K1_PROC(i + 3, a3);
    }
    for (int i = m4; i < end; ++i) {
        float4 a = embv[(size_t)s_tok[i] * 64 + lane];
        K1_PROC(i, a);
    }
    K1_FLUSH();
#undef K1_PROC
#undef K1_FLUSH
}

// ---------------------------------------------------------------------------
// k2: h = (seg_sum/max(counts,1)) @ W1^T + b1, fused BN column partials.
// 256 blocks x 16 rows; 4x4 micro-tile per thread (~10-15 us, LDS-bound).
// hout aliases seg_sum (rows staged to LDS first; blocks own disjoint rows).
// ---------------------------------------------------------------------------
#define KT2 32
__global__ __launch_bounds__(256) void k2_gemm_bn(
    const float* seg_sum, const float* __restrict__ counts,
    const float* __restrict__ W1, const float* __restrict__ b1,
    float* hout, float* __restrict__ colsum, float* __restrict__ colsq,
    float* __restrict__ out)
{
    __shared__ float s_bow[16][HID];
    __shared__ float s_w1t[KT2][HID + 1];
    __shared__ float s_cs[HID];
    __shared__ float s_cq[HID];
    const int tid = threadIdx.x;
    const int b0  = blockIdx.x * 16;

    if (blockIdx.x == 0 && tid == 0) out[0] = 0.f;   // k5 runs after k2
    s_cs[tid] = 0.f;
    s_cq[tid] = 0.f;

    const float4* ss4 = reinterpret_cast<const float4*>(seg_sum + (size_t)b0 * HID);
#pragma unroll
    for (int p = 0; p < 4; ++p) {
        int f  = p * 256 + tid;
        int r  = f >> 6, k4 = f & 63;
        float inv = 1.f / fmaxf(counts[b0 + r], 1.f);
        float4 v = ss4[f];
        v.x *= inv; v.y *= inv; v.z *= inv; v.w *= inv;
        *reinterpret_cast<float4*>(&s_bow[r][k4 * 4]) = v;
    }

    const int jr = tid >> 3;
    const int q  = tid & 7;
    const float4* __restrict__ W1v = reinterpret_cast<const float4*>(W1);

    float4 pre[8];
#pragma unroll
    for (int pass = 0; pass < 8; ++pass)
        pre[pass] = W1v[(size_t)(pass * 32 + jr) * 64 + q];

    const int cg = tid & 63;
    const int rg = tid >> 6;

    float acc[4][4];
    {
        float4 bj = reinterpret_cast<const float4*>(b1)[cg];
#pragma unroll
        for (int r = 0; r < 4; ++r) {
            acc[r][0] = bj.x; acc[r][1] = bj.y;
            acc[r][2] = bj.z; acc[r][3] = bj.w;
        }
    }

    for (int kt = 0; kt < HID / KT2; ++kt) {
        __syncthreads();
#pragma unroll
        for (int pass = 0; pass < 8; ++pass) {
            int j = pass * 32 + jr;
            float4 w = pre[pass];
            int kl = q * 4;
            s_w1t[kl + 0][j] = w.x;
            s_w1t[kl + 1][j] = w.y;
            s_w1t[kl + 2][j] = w.z;
            s_w1t[kl + 3][j] = w.w;
        }
        __syncthreads();
        if (kt + 1 < HID / KT2) {
#pragma unroll
            for (int pass = 0; pass < 8; ++pass)
                pre[pass] = W1v[(size_t)(pass * 32 + jr) * 64 + (kt + 1) * 8 + q];
        }
#pragma unroll
        for (int ks = 0; ks < 8; ++ks) {
            const int kg = kt * KT2 + ks * 4;
            const int kl = ks * 4;
            float4 bb0 = *reinterpret_cast<const float4*>(&s_bow[rg * 4 + 0][kg]);
            float4 bb1 = *reinterpret_cast<const float4*>(&s_bow[rg * 4 + 1][kg]);
            float4 bb2 = *reinterpret_cast<const float4*>(&s_bow[rg * 4 + 2][kg]);
            float4 bb3 = *reinterpret_cast<const float4*>(&s_bow[rg * 4 + 3][kg]);
            float4 w0 = *reinterpret_cast<const float4*>(&s_w1t[kl + 0][cg * 4]);
            float4 w1 = *reinterpret_cast<const float4*>(&s_w1t[kl + 1][cg * 4]);
            float4 w2 = *reinterpret_cast<const float4*>(&s_w1t[kl + 2][cg * 4]);
            float4 w3 = *reinterpret_cast<const float4*>(&s_w1t[kl + 3][cg * 4]);
#define K2_ROW(r, bb)                                                          \
            acc[r][0] = fmaf(bb.x, w0.x, fmaf(bb.y, w1.x,                      \
                        fmaf(bb.z, w2.x, fmaf(bb.w, w3.x, acc[r][0]))));       \
            acc[r][1] = fmaf(bb.x, w0.y, fmaf(bb.y, w1.y,                      \
                        fmaf(bb.z, w2.y, fmaf(bb.w, w3.y, acc[r][1]))));       \
            acc[r][2] = fmaf(bb.x, w0.z, fmaf(bb.y, w1.z,                      \
                        fmaf(bb.z, w2.z, fmaf(bb.w, w3.z, acc[r][2]))));       \
            acc[r][3] = fmaf(bb.x, w0.w, fmaf(bb.y, w1.w,                      \
                        fmaf(bb.z, w2.w, fmaf(bb.w, w3.w, acc[r][3]))));
            K2_ROW(0, bb0)
            K2_ROW(1, bb1)
            K2_ROW(2, bb2)
            K2_ROW(3, bb3)
#undef K2_ROW
        }
    }

#pragma unroll
    for (int r = 0; r < 4; ++r) {
        float4 v;
        v.x = acc[r][0]; v.y = acc[r][1]; v.z = acc[r][2]; v.w = acc[r][3];
        *reinterpret_cast<float4*>(
            &hout[(size_t)(b0 + rg * 4 + r) * HID + cg * 4]) = v;
    }
#pragma unroll
    for (int c = 0; c < 4; ++c) {
        float ps  = ((acc[0][c] + acc[1][c]) + (acc[2][c] + acc[3][c]));
        float psq = ((acc[0][c] * acc[0][c] + acc[1][c] * acc[1][c])
                   + (acc[2][c] * acc[2][c] + acc[3][c] * acc[3][c]));
        atomicAdd(&s_cs[cg * 4 + c], ps);
        atomicAdd(&s_cq[cg * 4 + c], psq);
    }
    __syncthreads();
    atomicAdd(&colsum[tid], s_cs[tid]);
    atomicAdd(&colsq[tid], s_cq[tid]);
}

// ---------------------------------------------------------------------------
// k5: BN finalize (folded) + apply + ReLU + logits + BCE loss.
// ---------------------------------------------------------------------------
__global__ __launch_bounds__(256) void k5_bn_relu_logits_loss(
    const float* __restrict__ hmat,
    const float* __restrict__ colsum, const float* __restrict__ colsq,
    const float* __restrict__ gamma, const float* __restrict__ beta,
    const float* __restrict__ W2, const float* __restrict__ b2,
    const float* __restrict__ labels, float* __restrict__ out)
{
    __shared__ float s_loss[4];
    const int tid  = threadIdx.x;
    const int w    = tid >> 6;
    const int lane = tid & 63;
    const int b0   = blockIdx.x * 16 + w * 4;

    const int j0 = lane, j1 = lane + 64, j2 = lane + 128, j3 = lane + 192;

#define BN_SS(jj, sc, sh) \
    { float mu = colsum[jj] * (1.f / BATCH); \
      float vr = colsq[jj] * (1.f / BATCH) - mu * mu; \
      sc = gamma[jj] * rsqrtf(vr + BN_EPS); \
      sh = beta[jj] - mu * sc; }
    float sc0, sh0, sc1, sh1, sc2, sh2, sc3, sh3;
    BN_SS(j0, sc0, sh0); BN_SS(j1, sc1, sh1);
    BN_SS(j2, sc2, sh2); BN_SS(j3, sc3, sh3);
#undef BN_SS

    const float w0 = W2[j0], w1 = W2[j1], w2v = W2[j2], w3 = W2[j3];
    const float bias2 = b2[0];

    float bce_acc = 0.f;
#pragma unroll
    for (int rr = 0; rr < 4; ++rr) {
        const int b = b0 + rr;
        const float* hr = hmat + (size_t)b * HID;
        float h0 = hr[j0], h1 = hr[j1], h2 = hr[j2], h3 = hr[j3];
        float s = 0.f;
        s += fmaxf(fmaf(h0, sc0, sh0), 0.f) * w0;
        s += fmaxf(fmaf(h1, sc1, sh1), 0.f) * w1;
        s += fmaxf(fmaf(h2, sc2, sh2), 0.f) * w2v;
        s += fmaxf(fmaf(h3, sc3, sh3), 0.f) * w3;
#pragma unroll
        for (int off = 32; off > 0; off >>= 1)
            s += __shfl_down(s, off, 64);
        if (lane == 0) {
            float z = s + bias2;
            out[1 + b] = z;
            float lb = labels[b];
            bce_acc += fmaxf(z, 0.f) - z * lb + log1pf(expf(-fabsf(z)));
        }
    }
    if (lane == 0) s_loss[w] = bce_acc;
    __syncthreads();
    if (tid == 0) {
        float t = (s_loss[0] + s_loss[1]) + (s_loss[2] + s_loss[3]);
        atomicAdd(&out[0], t * (1.f / BATCH));
    }
}

// ---------------------------------------------------------------------------
extern "C" void kernel_launch(void* const* d_in, const int* in_sizes, int n_in,
                              void* d_out, int out_size, void* d_ws, size_t ws_size,
                              hipStream_t stream)
{
    const int*   token_ids   = (const int*)d_in[0];
    const int*   segment_ids = (const int*)d_in[1];
    const float* labels      = (const float*)d_in[2];
    const float* emb         = (const float*)d_in[3];
    const float* W1          = (const float*)d_in[4];
    const float* b1          = (const float*)d_in[5];
    const float* gamma       = (const float*)d_in[6];
    const float* beta        = (const float*)d_in[7];
    const float* W2          = (const float*)d_in[8];
    const float* b2          = (const float*)d_in[9];
    float* out = (float*)d_out;
    float* ws  = (float*)d_ws;

    float* seg_sum = ws + WS_SEGSUM;   // reused as h after k2
    float* counts  = ws + WS_COUNTS;
    float* colsum  = ws + WS_COLSUM;
    float* colsq   = ws + WS_COLSQ;

    const int T = in_sizes[0];
    const int nrange = (T + TPB1 - 1) / TPB1;

    if (ws_size >= WS_FP16_BYTES_NEEDED) {
        __half* emb16 = (__half*)((char*)d_ws + WS_EMB16_OFF_BYTES);
        const int n4  = VOCAB * HID / 4;
        const int nz4 = WS_ZERO_FLOATS / 4;
        k0_convert_zero<<<(n4 + 255) / 256, 256, 0, stream>>>(
            emb, emb16, (float4*)d_ws, n4, nz4);
        k1_gather_fp16_cs<<<nrange * NSHARD, 256, 0, stream>>>(
            token_ids, segment_ids, emb16, seg_sum, counts, T);
    } else {
        hipMemsetAsync(d_ws, 0, (size_t)WS_ZERO_FLOATS * sizeof(float), stream);
        k1_gather_fp32<<<nrange, 256, 0, stream>>>(token_ids, segment_ids, emb,
                                                   seg_sum, counts, T);
    }
    k2_gemm_bn<<<BATCH / 16, 256, 0, stream>>>(
        seg_sum, counts, W1, b1, /*hout=*/seg_sum, colsum, colsq, out);
    k5_bn_relu_logits_loss<<<BATCH / 16, 256, 0, stream>>>(
        seg_sum, colsum, colsq, gamma, beta, W2, b2, labels, out);
}

// Round 8
// 278.489 us; speedup vs baseline: 2.1874x; 2.1874x over previous
//
#include <hip/hip_runtime.h>
#include <hip/hip_fp16.h>
#include <math.h>

#define VOCAB 100000
#define HID 256
#define BATCH 4096
#define BN_EPS 1e-5f
#define TPB1 512      // tokens per block in k1 (4 waves x 128 tokens)

// ws layout (in floats)
#define WS_SEGSUM 0
#define WS_COUNTS (BATCH * HID)            // 1048576
#define WS_COLSUM (WS_COUNTS + BATCH)
#define WS_COLSQ  (WS_COLSUM + HID)
#define WS_ZERO_FLOATS (WS_COLSQ + HID)    // 1053184 floats; zero-filled by k0
#define WS_EMB16_OFF_BYTES ((size_t)WS_ZERO_FLOATS * 4)   // 16B-aligned
#define WS_FP16_BYTES_NEEDED (WS_EMB16_OFF_BYTES + (size_t)VOCAB * HID * 2)

// ---------------------------------------------------------------------------
// k0: emb fp32 -> fp16 table in ws; also zeroes the accumulator region.
// Byte-bound floor: ~153 MB traffic ~= 27 us.
// ---------------------------------------------------------------------------
__global__ __launch_bounds__(256) void k0_convert_zero(
    const float* __restrict__ emb, __half* __restrict__ emb16,
    float4* __restrict__ zws, int n4, int nz4)
{
    int i = blockIdx.x * 256 + threadIdx.x;
    if (i < nz4) zws[i] = make_float4(0.f, 0.f, 0.f, 0.f);
    if (i >= n4) return;
    float4 v = reinterpret_cast<const float4*>(emb)[i];
    __half2 a = __halves2half2(__float2half_rn(v.x), __float2half_rn(v.y));
    __half2 b = __halves2half2(__float2half_rn(v.z), __float2half_rn(v.w));
    uint2 o;
    o.x = __builtin_bit_cast(unsigned int, a);
    o.y = __builtin_bit_cast(unsigned int, b);
    reinterpret_cast<uint2*>(emb16)[i] = o;
}

// ---------------------------------------------------------------------------
// k1 v2 (fp16 table) — PROVEN BEST (r3/r4: 74 us, ~90% of the 67 us
// demand-byte floor). Wave owns 128 contiguous tokens; lane owns 4 hidden
// columns (uint2 = 8B/lane, 512B/wave-load); 8 independent token loads in
// flight. Sorted segment_ids -> wave-uniform register run accumulation,
// coalesced atomic flush at run boundaries only (WRITE ~42 MB).
// DO NOT split the wave's one-row-read / one-flush-group structure:
//  - r5 per-half-wave pairing: WRITE x4, 186 us.
//  - r6 token-sharding (%8): runs x8 -> WRITE x8, 289 us.
//  - r7 column-sharding: flushes x64, stride-8 reads -> FETCH+WRITE up, 412 us.
// ---------------------------------------------------------------------------
__global__ __launch_bounds__(256) void k1_gather_fp16(
    const int* __restrict__ token_ids, const int* __restrict__ segment_ids,
    const __half* __restrict__ emb16, float* __restrict__ seg_sum,
    float* __restrict__ counts, int T)
{
    __shared__ int s_tok[TPB1];
    __shared__ int s_seg[TPB1];
    const int tid = threadIdx.x;
    const int t0  = blockIdx.x * TPB1;
    const int n   = min(TPB1, T - t0);
    if (n <= 0) return;
    for (int i = tid; i < n; i += 256) {
        s_tok[i] = token_ids[t0 + i];
        s_seg[i] = segment_ids[t0 + i];
    }
    __syncthreads();

    const int wave = tid >> 6;
    const int lane = tid & 63;
    const int per  = TPB1 / 4;
    const int start = wave * per;
    const int end   = min(start + per, n);
    if (start >= end) return;

    const uint2* __restrict__ embv = reinterpret_cast<const uint2*>(emb16);
    float4 acc = make_float4(0.f, 0.f, 0.f, 0.f);
    int cur = s_seg[start];
    int runlen = 0;

#define K1_FLUSH() do {                                                        \
        float* p = &seg_sum[(size_t)cur * HID + lane * 4];                     \
        atomicAdd(p + 0, acc.x); atomicAdd(p + 1, acc.y);                      \
        atomicAdd(p + 2, acc.z); atomicAdd(p + 3, acc.w);                      \
        if (lane == 0) atomicAdd(&counts[cur], (float)runlen);                 \
        acc = make_float4(0.f, 0.f, 0.f, 0.f); runlen = 0;                     \
    } while (0)

#define K1_PROC16(ii, u) do {                                                  \
        int seg = s_seg[ii];               /* LDS broadcast, wave-uniform */   \
        if (seg != cur) { K1_FLUSH(); cur = seg; }                             \
        __half2 h01 = __builtin_bit_cast(__half2, (u).x);                      \
        __half2 h23 = __builtin_bit_cast(__half2, (u).y);                      \
        float2 f01 = __half22float2(h01);                                      \
        float2 f23 = __half22float2(h23);                                      \
        acc.x += f01.x; acc.y += f01.y; acc.z += f23.x; acc.w += f23.y;        \
        runlen++;                                                              \
    } while (0)

    const int m8 = start + ((end - start) & ~7);
    for (int i = start; i < m8; i += 8) {
        uint2 u0 = embv[(size_t)s_tok[i + 0] * 64 + lane];
        uint2 u1 = embv[(size_t)s_tok[i + 1] * 64 + lane];
        uint2 u2 = embv[(size_t)s_tok[i + 2] * 64 + lane];
        uint2 u3 = embv[(size_t)s_tok[i + 3] * 64 + lane];
        uint2 u4 = embv[(size_t)s_tok[i + 4] * 64 + lane];
        uint2 u5 = embv[(size_t)s_tok[i + 5] * 64 + lane];
        uint2 u6 = embv[(size_t)s_tok[i + 6] * 64 + lane];
        uint2 u7 = embv[(size_t)s_tok[i + 7] * 64 + lane];
        K1_PROC16(i + 0, u0); K1_PROC16(i + 1, u1);
        K1_PROC16(i + 2, u2); K1_PROC16(i + 3, u3);
        K1_PROC16(i + 4, u4); K1_PROC16(i + 5, u5);
        K1_PROC16(i + 6, u6); K1_PROC16(i + 7, u7);
    }
    for (int i = m8; i < end; ++i) {
        uint2 u = embv[(size_t)s_tok[i] * 64 + lane];
        K1_PROC16(i, u);
    }
    K1_FLUSH();
#undef K1_PROC16
#undef K1_FLUSH
}

// ---------------------------------------------------------------------------
// k1 (fp32 fallback, only if ws too small for the fp16 table).
// ---------------------------------------------------------------------------
__global__ __launch_bounds__(256) void k1_gather_fp32(
    const int* __restrict__ token_ids, const int* __restrict__ segment_ids,
    const float* __restrict__ emb, float* __restrict__ seg_sum,
    float* __restrict__ counts, int T)
{
    __shared__ int s_tok[TPB1];
    __shared__ int s_seg[TPB1];
    const int tid = threadIdx.x;
    const int t0  = blockIdx.x * TPB1;
    const int n   = min(TPB1, T - t0);
    if (n <= 0) return;
    for (int i = tid; i < n; i += 256) {
        s_tok[i] = token_ids[t0 + i];
        s_seg[i] = segment_ids[t0 + i];
    }
    __syncthreads();

    const int wave = tid >> 6;
    const int lane = tid & 63;
    const int per  = TPB1 / 4;
    const int start = wave * per;
    const int end   = min(start + per, n);
    if (start >= end) return;

    const float4* __restrict__ embv = reinterpret_cast<const float4*>(emb);
    float4 acc = make_float4(0.f, 0.f, 0.f, 0.f);
    int cur = s_seg[start];
    int runlen = 0;

#define K1_FLUSH() do {                                                        \
        float* p = &seg_sum[(size_t)cur * HID + lane * 4];                     \
        atomicAdd(p + 0, acc.x); atomicAdd(p + 1, acc.y);                      \
        atomicAdd(p + 2, acc.z); atomicAdd(p + 3, acc.w);                      \
        if (lane == 0) atomicAdd(&counts[cur], (float)runlen);                 \
        acc = make_float4(0.f, 0.f, 0.f, 0.f); runlen = 0;                     \
    } while (0)

#define K1_PROC(ii, v) do {                                                    \
        int seg = s_seg[ii];                                                   \
        if (seg != cur) { K1_FLUSH(); cur = seg; }                             \
        acc.x += (v).x; acc.y += (v).y; acc.z += (v).z; acc.w += (v).w;        \
        runlen++;                                                              \
    } while (0)

    const int m4 = start + ((end - start) & ~3);
    for (int i = start; i < m4; i += 4) {
        float4 a0 = embv[(size_t)s_tok[i + 0] * 64 + lane];
        float4 a1 = embv[(size_t)s_tok[i + 1] * 64 + lane];
        float4 a2 = embv[(size_t)s_tok[i + 2] * 64 + lane];
        float4 a3 = embv[(size_t)s_tok[i + 3] * 64 + lane];
        K1_PROC(i + 0, a0); K1_PROC(i + 1, a1);
        K1_PROC(i + 2, a2); K1_PROC(i + 3, a3);
    }
    for (int i = m4; i < end; ++i) {
        float4 a = embv[(size_t)s_tok[i] * 64 + lane];
        K1_PROC(i, a);
    }
    K1_FLUSH();
#undef K1_PROC
#undef K1_FLUSH
}

// ---------------------------------------------------------------------------
// k2: h = (seg_sum/max(counts,1)) @ W1^T + b1, fused BN column partials.
// 256 blocks x 16 rows; 4x4 micro-tile per thread (~10 us, LDS-bound).
// hout aliases seg_sum (rows staged to LDS first; blocks own disjoint rows).
// ---------------------------------------------------------------------------
#define KT2 32
__global__ __launch_bounds__(256) void k2_gemm_bn(
    const float* seg_sum, const float* __restrict__ counts,
    const float* __restrict__ W1, const float* __restrict__ b1,
    float* hout, float* __restrict__ colsum, float* __restrict__ colsq,
    float* __restrict__ out)
{
    __shared__ float s_bow[16][HID];
    __shared__ float s_w1t[KT2][HID + 1];
    __shared__ float s_cs[HID];
    __shared__ float s_cq[HID];
    const int tid = threadIdx.x;
    const int b0  = blockIdx.x * 16;

    if (blockIdx.x == 0 && tid == 0) out[0] = 0.f;   // k5 runs after k2
    s_cs[tid] = 0.f;
    s_cq[tid] = 0.f;

    const float4* ss4 = reinterpret_cast<const float4*>(seg_sum + (size_t)b0 * HID);
#pragma unroll
    for (int p = 0; p < 4; ++p) {
        int f  = p * 256 + tid;
        int r  = f >> 6, k4 = f & 63;
        float inv = 1.f / fmaxf(counts[b0 + r], 1.f);
        float4 v = ss4[f];
        v.x *= inv; v.y *= inv; v.z *= inv; v.w *= inv;
        *reinterpret_cast<float4*>(&s_bow[r][k4 * 4]) = v;
    }

    const int jr = tid >> 3;
    const int q  = tid & 7;
    const float4* __restrict__ W1v = reinterpret_cast<const float4*>(W1);

    float4 pre[8];
#pragma unroll
    for (int pass = 0; pass < 8; ++pass)
        pre[pass] = W1v[(size_t)(pass * 32 + jr) * 64 + q];

    const int cg = tid & 63;
    const int rg = tid >> 6;

    float acc[4][4];
    {
        float4 bj = reinterpret_cast<const float4*>(b1)[cg];
#pragma unroll
        for (int r = 0; r < 4; ++r) {
            acc[r][0] = bj.x; acc[r][1] = bj.y;
            acc[r][2] = bj.z; acc[r][3] = bj.w;
        }
    }

    for (int kt = 0; kt < HID / KT2; ++kt) {
        __syncthreads();
#pragma unroll
        for (int pass = 0; pass < 8; ++pass) {
            int j = pass * 32 + jr;
            float4 w = pre[pass];
            int kl = q * 4;
            s_w1t[kl + 0][j] = w.x;
            s_w1t[kl + 1][j] = w.y;
            s_w1t[kl + 2][j] = w.z;
            s_w1t[kl + 3][j] = w.w;
        }
        __syncthreads();
        if (kt + 1 < HID / KT2) {
#pragma unroll
            for (int pass = 0; pass < 8; ++pass)
                pre[pass] = W1v[(size_t)(pass * 32 + jr) * 64 + (kt + 1) * 8 + q];
        }
#pragma unroll
        for (int ks = 0; ks < 8; ++ks) {
            const int kg = kt * KT2 + ks * 4;
            const int kl = ks * 4;
            float4 bb0 = *reinterpret_cast<const float4*>(&s_bow[rg * 4 + 0][kg]);
            float4 bb1 = *reinterpret_cast<const float4*>(&s_bow[rg * 4 + 1][kg]);
            float4 bb2 = *reinterpret_cast<const float4*>(&s_bow[rg * 4 + 2][kg]);
            float4 bb3 = *reinterpret_cast<const float4*>(&s_bow[rg * 4 + 3][kg]);
            float4 w0 = *reinterpret_cast<const float4*>(&s_w1t[kl + 0][cg * 4]);
            float4 w1 = *reinterpret_cast<const float4*>(&s_w1t[kl + 1][cg * 4]);
            float4 w2 = *reinterpret_cast<const float4*>(&s_w1t[kl + 2][cg * 4]);
            float4 w3 = *reinterpret_cast<const float4*>(&s_w1t[kl + 3][cg * 4]);
#define K2_ROW(r, bb)                                                          \
            acc[r][0] = fmaf(bb.x, w0.x, fmaf(bb.y, w1.x,                      \
                        fmaf(bb.z, w2.x, fmaf(bb.w, w3.x, acc[r][0]))));       \
            acc[r][1] = fmaf(bb.x, w0.y, fmaf(bb.y, w1.y,                      \
                        fmaf(bb.z, w2.y, fmaf(bb.w, w3.y, acc[r][1]))));       \
            acc[r][2] = fmaf(bb.x, w0.z, fmaf(bb.y, w1.z,                      \
                        fmaf(bb.z, w2.z, fmaf(bb.w, w3.z, acc[r][2]))));       \
            acc[r][3] = fmaf(bb.x, w0.w, fmaf(bb.y, w1.w,                      \
                        fmaf(bb.z, w2.w, fmaf(bb.w, w3.w, acc[r][3]))));
            K2_ROW(0, bb0)
            K2_ROW(1, bb1)
            K2_ROW(2, bb2)
            K2_ROW(3, bb3)
#undef K2_ROW
        }
    }

#pragma unroll
    for (int r = 0; r < 4; ++r) {
        float4 v;
        v.x = acc[r][0]; v.y = acc[r][1]; v.z = acc[r][2]; v.w = acc[r][3];
        *reinterpret_cast<float4*>(
            &hout[(size_t)(b0 + rg * 4 + r) * HID + cg * 4]) = v;
    }
#pragma unroll
    for (int c = 0; c < 4; ++c) {
        float ps  = ((acc[0][c] + acc[1][c]) + (acc[2][c] + acc[3][c]));
        float psq = ((acc[0][c] * acc[0][c] + acc[1][c] * acc[1][c])
                   + (acc[2][c] * acc[2][c] + acc[3][c] * acc[3][c]));
        atomicAdd(&s_cs[cg * 4 + c], ps);
        atomicAdd(&s_cq[cg * 4 + c], psq);
    }
    __syncthreads();
    atomicAdd(&colsum[tid], s_cs[tid]);
    atomicAdd(&colsq[tid], s_cq[tid]);
}

// ---------------------------------------------------------------------------
// k5: BN finalize (folded) + apply + ReLU + logits + BCE loss.
// out[0] = loss, out[1..BATCH] = logits.
// ---------------------------------------------------------------------------
__global__ __launch_bounds__(256) void k5_bn_relu_logits_loss(
    const float* __restrict__ hmat,
    const float* __restrict__ colsum, const float* __restrict__ colsq,
    const float* __restrict__ gamma, const float* __restrict__ beta,
    const float* __restrict__ W2, const float* __restrict__ b2,
    const float* __restrict__ labels, float* __restrict__ out)
{
    __shared__ float s_loss[4];
    const int tid  = threadIdx.x;
    const int w    = tid >> 6;
    const int lane = tid & 63;
    const int b0   = blockIdx.x * 16 + w * 4;

    const int j0 = lane, j1 = lane + 64, j2 = lane + 128, j3 = lane + 192;

#define BN_SS(jj, sc, sh) \
    { float mu = colsum[jj] * (1.f / BATCH); \
      float vr = colsq[jj] * (1.f / BATCH) - mu * mu; \
      sc = gamma[jj] * rsqrtf(vr + BN_EPS); \
      sh = beta[jj] - mu * sc; }
    float sc0, sh0, sc1, sh1, sc2, sh2, sc3, sh3;
    BN_SS(j0, sc0, sh0); BN_SS(j1, sc1, sh1);
    BN_SS(j2, sc2, sh2); BN_SS(j3, sc3, sh3);
#undef BN_SS

    const float w0 = W2[j0], w1 = W2[j1], w2v = W2[j2], w3 = W2[j3];
    const float bias2 = b2[0];

    float bce_acc = 0.f;
#pragma unroll
    for (int rr = 0; rr < 4; ++rr) {
        const int b = b0 + rr;
        const float* hr = hmat + (size_t)b * HID;
        float h0 = hr[j0], h1 = hr[j1], h2 = hr[j2], h3 = hr[j3];
        float s = 0.f;
        s += fmaxf(fmaf(h0, sc0, sh0), 0.f) * w0;
        s += fmaxf(fmaf(h1, sc1, sh1), 0.f) * w1;
        s += fmaxf(fmaf(h2, sc2, sh2), 0.f) * w2v;
        s += fmaxf(fmaf(h3, sc3, sh3), 0.f) * w3;
#pragma unroll
        for (int off = 32; off > 0; off >>= 1)
            s += __shfl_down(s, off, 64);
        if (lane == 0) {
            float z = s + bias2;
            out[1 + b] = z;
            float lb = labels[b];
            bce_acc += fmaxf(z, 0.f) - z * lb + log1pf(expf(-fabsf(z)));
        }
    }
    if (lane == 0) s_loss[w] = bce_acc;
    __syncthreads();
    if (tid == 0) {
        float t = (s_loss[0] + s_loss[1]) + (s_loss[2] + s_loss[3]);
        atomicAdd(&out[0], t * (1.f / BATCH));
    }
}

// ---------------------------------------------------------------------------
extern "C" void kernel_launch(void* const* d_in, const int* in_sizes, int n_in,
                              void* d_out, int out_size, void* d_ws, size_t ws_size,
                              hipStream_t stream)
{
    const int*   token_ids   = (const int*)d_in[0];
    const int*   segment_ids = (const int*)d_in[1];
    const float* labels      = (const float*)d_in[2];
    const float* emb         = (const float*)d_in[3];
    const float* W1          = (const float*)d_in[4];
    const float* b1          = (const float*)d_in[5];
    const float* gamma       = (const float*)d_in[6];
    const float* beta        = (const float*)d_in[7];
    const float* W2          = (const float*)d_in[8];
    const float* b2          = (const float*)d_in[9];
    float* out = (float*)d_out;
    float* ws  = (float*)d_ws;

    float* seg_sum = ws + WS_SEGSUM;   // reused as h after k2
    float* counts  = ws + WS_COUNTS;
    float* colsum  = ws + WS_COLSUM;
    float* colsq   = ws + WS_COLSQ;

    const int T = in_sizes[0];
    const int g1 = (T + TPB1 - 1) / TPB1;

    if (ws_size >= WS_FP16_BYTES_NEEDED) {
        __half* emb16 = (__half*)((char*)d_ws + WS_EMB16_OFF_BYTES);
        const int n4  = VOCAB * HID / 4;
        const int nz4 = WS_ZERO_FLOATS / 4;
        k0_convert_zero<<<(n4 + 255) / 256, 256, 0, stream>>>(
            emb, emb16, (float4*)d_ws, n4, nz4);
        k1_gather_fp16<<<g1, 256, 0, stream>>>(token_ids, segment_ids, emb16,
                                               seg_sum, counts, T);
    } else {
        hipMemsetAsync(d_ws, 0, (size_t)WS_ZERO_FLOATS * sizeof(float), stream);
        k1_gather_fp32<<<g1, 256, 0, stream>>>(token_ids, segment_ids, emb,
                                               seg_sum, counts, T);
    }
    k2_gemm_bn<<<BATCH / 16, 256, 0, stream>>>(
        seg_sum, counts, W1, b1, /*hout=*/seg_sum, colsum, colsq, out);
    k5_bn_relu_logits_loss<<<BATCH / 16, 256, 0, stream>>>(
        seg_sum, colsum, colsq, gamma, beta, W2, b2, labels, out);
}